// Round 1
// baseline (251.158 us; speedup 1.0000x reference)
//
#include <hip/hip_runtime.h>
#include <hip/hip_bf16.h>
#include <cstdint>

typedef unsigned short u16;
typedef __attribute__((ext_vector_type(8))) short bf16x8;
typedef __attribute__((ext_vector_type(4))) float f32x4;

#define S_LEN 1024
#define BATCH 8
#define DMODEL 256
#define NHEAD 8
#define HDIM 32
#define DFF 1024
#define NROWS (S_LEN * BATCH)   // 8192

static __device__ __forceinline__ u16 f2b(float f) {
    union { float f; unsigned u; } x{f};
    unsigned r = (x.u + 0x7fffu + ((x.u >> 16) & 1u)) >> 16;
    return (u16)r;
}

// ---------------------------------------------------------------------------
// Weight conversion: f32 -> bf16, q-scale folded into Wq rows and bq.
// ---------------------------------------------------------------------------
__global__ __launch_bounds__(256) void convert_weights(
    const float* __restrict__ ipw, const float* __restrict__ outw,
    const float* __restrict__ w1, const float* __restrict__ w2,
    const float* __restrict__ ipb,
    u16* __restrict__ wqkv, u16* __restrict__ wout,
    u16* __restrict__ w1b, u16* __restrict__ w2b, float* __restrict__ bq)
{
    const float s = 0.17677669529663689f; // 1/sqrt(32)
    int i = blockIdx.x * 256 + threadIdx.x;
    if (i < 196608) {
        float v = ipw[i];
        if (i < 65536) v *= s;
        wqkv[i] = f2b(v);
    } else if (i < 262144) {
        wout[i - 196608] = f2b(outw[i - 196608]);
    } else if (i < 524288) {
        w1b[i - 262144] = f2b(w1[i - 262144]);
    } else if (i < 786432) {
        w2b[i - 524288] = f2b(w2[i - 524288]);
    }
    if (i < 768) bq[i] = ipb[i] * (i < 256 ? s : 1.0f);
}

// ---------------------------------------------------------------------------
// LayerNorm: one wave per row of 256; outputs f32 and bf16 copies.
// ---------------------------------------------------------------------------
__global__ __launch_bounds__(256) void ln_kernel(
    const float* __restrict__ in, const float* __restrict__ g,
    const float* __restrict__ be, float* __restrict__ of, u16* __restrict__ ob)
{
    const int w = threadIdx.x >> 6, l = threadIdx.x & 63;
    const int row = blockIdx.x * 4 + w;
    const float4 v = *(const float4*)(in + (size_t)row * DMODEL + l * 4);
    float s = v.x + v.y + v.z + v.w;
    #pragma unroll
    for (int o = 32; o; o >>= 1) s += __shfl_xor(s, o);
    const float mu = s * (1.0f / DMODEL);
    const float dx = v.x - mu, dy = v.y - mu, dz = v.z - mu, dw = v.w - mu;
    float sq = dx * dx + dy * dy + dz * dz + dw * dw;
    #pragma unroll
    for (int o = 32; o; o >>= 1) sq += __shfl_xor(sq, o);
    const float rs = rsqrtf(sq * (1.0f / DMODEL) + 1e-5f);
    const float4 gv = *(const float4*)(g + l * 4);
    const float4 bv = *(const float4*)(be + l * 4);
    const float r0 = dx * rs * gv.x + bv.x;
    const float r1 = dy * rs * gv.y + bv.y;
    const float r2 = dz * rs * gv.z + bv.z;
    const float r3 = dw * rs * gv.w + bv.w;
    *(float4*)(of + (size_t)row * DMODEL + l * 4) = make_float4(r0, r1, r2, r3);
    uint2 pk;
    pk.x = (unsigned)f2b(r0) | ((unsigned)f2b(r1) << 16);
    pk.y = (unsigned)f2b(r2) | ((unsigned)f2b(r3) << 16);
    *(uint2*)(ob + (size_t)row * DMODEL + l * 4) = pk;
}

// ---------------------------------------------------------------------------
// GEMM  C[M,N] = A[M,K] @ Bw[N,K]^T (+bias, epilogue by MODE)
// MODE 0: store bf16 (QKV).  1: +resid -> f32 (outproj).
// MODE 2: relu -> bf16 (FFN1). 3: +resid -> f32 (FFN2 -> d_out).
// block = 256 thr (4 waves), tile 64(M) x 64(N), BK=64, LDS-staged A.
// ---------------------------------------------------------------------------
template <int MODE>
__global__ __launch_bounds__(256) void gemm_bt(
    const u16* __restrict__ A, const u16* __restrict__ Bw,
    const float* __restrict__ bias, const float* __restrict__ resid,
    float* __restrict__ outf, u16* __restrict__ outb,
    int M, int N, int K)
{
    __shared__ u16 sA[64 * 64];
    const int tid = threadIdx.x, w = tid >> 6, l = tid & 63;
    const int rowbase = blockIdx.x * 64, nbase = blockIdx.y * 64;
    f32x4 acc[4] = {{0,0,0,0},{0,0,0,0},{0,0,0,0},{0,0,0,0}};

    for (int kk = 0; kk < K; kk += 64) {
        __syncthreads();
        #pragma unroll
        for (int it = 0; it < 2; ++it) {
            const int idx = it * 256 + tid;
            const int row = idx >> 3, seg = idx & 7;
            const uint4 v = *(const uint4*)(A + (size_t)(rowbase + row) * K + kk + seg * 8);
            *(uint4*)(&sA[(row * 128 + ((seg * 16) ^ ((row & 7) << 4))) >> 1]) = v;
        }
        __syncthreads();
        #pragma unroll
        for (int ks = 0; ks < 2; ++ks) {
            const int arow = w * 16 + (l & 15);
            const bf16x8 af = *(const bf16x8*)(
                &sA[(arow * 128 + (((ks * 64 + (l >> 4) * 16)) ^ ((arow & 7) << 4))) >> 1]);
            #pragma unroll
            for (int n = 0; n < 4; ++n) {
                const bf16x8 bf = *(const bf16x8*)(
                    Bw + (size_t)(nbase + n * 16 + (l & 15)) * K + kk + ks * 32 + (l >> 4) * 8);
                acc[n] = __builtin_amdgcn_mfma_f32_16x16x32_bf16(af, bf, acc[n], 0, 0, 0);
            }
        }
    }

    #pragma unroll
    for (int n = 0; n < 4; ++n) {
        #pragma unroll
        for (int r = 0; r < 4; ++r) {
            const int row = rowbase + w * 16 + (l >> 4) * 4 + r;
            const int col = nbase + n * 16 + (l & 15);
            float v = acc[n][r] + bias[col];
            if (MODE == 0) {
                outb[(size_t)row * N + col] = f2b(v);
            } else if (MODE == 1) {
                outf[(size_t)row * N + col] = v + resid[(size_t)row * N + col];
            } else if (MODE == 2) {
                outb[(size_t)row * N + col] = f2b(fmaxf(v, 0.0f));
            } else {
                outf[(size_t)row * N + col] = v + resid[(size_t)row * N + col];
            }
        }
    }
}

// ---------------------------------------------------------------------------
// Reshape qkv [8192,768] -> Q [BH,S,HD], K [BH,S,HD], Vt [BH,HD,S] (bf16)
// ---------------------------------------------------------------------------
__global__ __launch_bounds__(256) void reshape_qkv(
    const u16* __restrict__ qkv, u16* __restrict__ Q,
    u16* __restrict__ Kd, u16* __restrict__ Vt)
{
    const int g = blockIdx.x * 256 + threadIdx.x;   // 786432 total
    const int i = g / 96;
    const int c8 = (g - i * 96) * 8;
    const int srow = i >> 3, b = i & 7;
    const uint4 v = *(const uint4*)(qkv + (size_t)i * 768 + c8);
    const int part = c8 >> 8;
    const int cc = c8 & 255;
    const int h = cc >> 5, hd = cc & 31;
    const int bh = b * NHEAD + h;
    if (part == 0) {
        *(uint4*)(Q + ((size_t)bh * S_LEN + srow) * HDIM + hd) = v;
    } else if (part == 1) {
        *(uint4*)(Kd + ((size_t)bh * S_LEN + srow) * HDIM + hd) = v;
    } else {
        const u16* pv = (const u16*)&v;
        #pragma unroll
        for (int e = 0; e < 8; ++e)
            Vt[((size_t)bh * HDIM + hd + e) * S_LEN + srow] = pv[e];
    }
}

// ---------------------------------------------------------------------------
// Flash attention with additive bias.
// grid (S/64, B*H), 256 thr (4 waves). Wave w: 16 q-rows. K-tiles of 64.
// ---------------------------------------------------------------------------
__global__ __launch_bounds__(256) void attn_kernel(
    const u16* __restrict__ Q, const u16* __restrict__ Kd,
    const u16* __restrict__ Vt, const float* __restrict__ bias,
    u16* __restrict__ ctx)
{
    __shared__ u16 sK[64 * 32];
    __shared__ u16 sV[32 * 64];
    __shared__ u16 sP[4][16 * 64];
    const int tid = threadIdx.x, w = tid >> 6, l = tid & 63;
    const int bh = blockIdx.y;
    const int b = bh >> 3, h = bh & 7;
    const int qbase = blockIdx.x * 64 + w * 16;

    const bf16x8 qf = *(const bf16x8*)(
        Q + ((size_t)bh * S_LEN + qbase + (l & 15)) * HDIM + (l >> 4) * 8);

    f32x4 ctxa[2] = {{0,0,0,0},{0,0,0,0}};
    float m[4] = {-1e30f, -1e30f, -1e30f, -1e30f};
    float lsum[4] = {0, 0, 0, 0};
    const float* brow = bias + ((size_t)bh * S_LEN + qbase) * S_LEN;

    for (int kt = 0; kt < S_LEN / 64; ++kt) {
        __syncthreads();
        {
            const int row = tid >> 2, seg = tid & 3;
            *(uint4*)(&sK[(row * 64 + ((seg * 16) ^ ((row & 3) << 4))) >> 1]) =
                *(const uint4*)(Kd + ((size_t)bh * S_LEN + kt * 64 + row) * HDIM + seg * 8);
            const int vrow = tid >> 3, vseg = tid & 7;
            *(uint4*)(&sV[(vrow * 128 + ((vseg * 16) ^ ((vrow & 7) << 4))) >> 1]) =
                *(const uint4*)(Vt + ((size_t)bh * HDIM + vrow) * S_LEN + kt * 64 + vseg * 8);
        }
        __syncthreads();

        // S = Q @ K^T
        f32x4 sc[4];
        #pragma unroll
        for (int n = 0; n < 4; ++n) {
            const int krow = n * 16 + (l & 15);
            const bf16x8 kf = *(const bf16x8*)(
                &sK[(krow * 64 + (((l >> 4) * 16) ^ ((krow & 3) << 4))) >> 1]);
            f32x4 z = {0, 0, 0, 0};
            sc[n] = __builtin_amdgcn_mfma_f32_16x16x32_bf16(qf, kf, z, 0, 0, 0);
        }
        // + bias
        #pragma unroll
        for (int n = 0; n < 4; ++n)
            #pragma unroll
            for (int r = 0; r < 4; ++r)
                sc[n][r] += brow[(size_t)((l >> 4) * 4 + r) * S_LEN + kt * 64 + n * 16 + (l & 15)];

        // online softmax (rows live in lanes sharing l>>4; reduce across l&15)
        float p[4][4];
        #pragma unroll
        for (int r = 0; r < 4; ++r) {
            float mx = fmaxf(fmaxf(sc[0][r], sc[1][r]), fmaxf(sc[2][r], sc[3][r]));
            #pragma unroll
            for (int o = 8; o; o >>= 1) mx = fmaxf(mx, __shfl_xor(mx, o));
            const float mn = fmaxf(m[r], mx);
            const float corr = __expf(m[r] - mn);
            float su = 0.0f;
            #pragma unroll
            for (int n = 0; n < 4; ++n) {
                const float pv = __expf(sc[n][r] - mn);
                p[n][r] = pv;
                su += pv;
            }
            #pragma unroll
            for (int o = 8; o; o >>= 1) su += __shfl_xor(su, o);
            lsum[r] = lsum[r] * corr + su;
            m[r] = mn;
            ctxa[0][r] *= corr;
            ctxa[1][r] *= corr;
        }

        // P -> LDS (per-wave), swizzled
        u16* Pw = sP[w];
        #pragma unroll
        for (int n = 0; n < 4; ++n)
            #pragma unroll
            for (int r = 0; r < 4; ++r) {
                const int prow = (l >> 4) * 4 + r, pcol = n * 16 + (l & 15);
                Pw[(prow * 128 + ((pcol * 2) ^ ((prow & 7) << 4))) >> 1] = f2b(p[n][r]);
            }

        // ctx += P @ V
        #pragma unroll
        for (int ks = 0; ks < 2; ++ks) {
            const int prow = l & 15;
            const bf16x8 pf = *(const bf16x8*)(
                &Pw[(prow * 128 + ((ks * 64 + (l >> 4) * 16) ^ ((prow & 7) << 4))) >> 1]);
            #pragma unroll
            for (int jg = 0; jg < 2; ++jg) {
                const int vrow = jg * 16 + (l & 15);
                const bf16x8 vf = *(const bf16x8*)(
                    &sV[(vrow * 128 + ((ks * 64 + (l >> 4) * 16) ^ ((vrow & 7) << 4))) >> 1]);
                ctxa[jg] = __builtin_amdgcn_mfma_f32_16x16x32_bf16(pf, vf, ctxa[jg], 0, 0, 0);
            }
        }
    }

    // write ctx -> [S,B,D] bf16
    #pragma unroll
    for (int jg = 0; jg < 2; ++jg)
        #pragma unroll
        for (int r = 0; r < 4; ++r) {
            const int srow = qbase + (l >> 4) * 4 + r;
            const float v = ctxa[jg][r] / lsum[r];
            ctx[((size_t)srow * BATCH + b) * DMODEL + h * HDIM + jg * 16 + (l & 15)] = f2b(v);
        }
}

// ---------------------------------------------------------------------------
extern "C" void kernel_launch(void* const* d_in, const int* in_sizes, int n_in,
                              void* d_out, int out_size, void* d_ws, size_t ws_size,
                              hipStream_t stream)
{
    const float* src  = (const float*)d_in[0];
    const float* bias = (const float*)d_in[1];
    const float* ipw  = (const float*)d_in[2];
    const float* ipb  = (const float*)d_in[3];
    const float* outw = (const float*)d_in[4];
    const float* outb = (const float*)d_in[5];
    const float* w1   = (const float*)d_in[6];
    const float* b1   = (const float*)d_in[7];
    const float* w2   = (const float*)d_in[8];
    const float* b2   = (const float*)d_in[9];
    const float* g1   = (const float*)d_in[10];
    const float* be1  = (const float*)d_in[11];
    const float* g2   = (const float*)d_in[12];
    const float* be2  = (const float*)d_in[13];

    char* p = (char*)d_ws;
    auto alloc = [&](size_t bytes) -> void* {
        void* r = (void*)p;
        p += (bytes + 255) & ~(size_t)255;
        return r;
    };
    float* xf   = (float*)alloc((size_t)NROWS * DMODEL * 4);
    u16*   xb   = (u16*)  alloc((size_t)NROWS * DMODEL * 2);
    u16*   qkv  = (u16*)  alloc((size_t)NROWS * 768 * 2);
    u16*   Qb   = (u16*)  alloc((size_t)64 * S_LEN * HDIM * 2);
    u16*   Kb   = (u16*)  alloc((size_t)64 * S_LEN * HDIM * 2);
    u16*   Vt   = (u16*)  alloc((size_t)64 * S_LEN * HDIM * 2);
    u16*   ctx  = (u16*)  alloc((size_t)NROWS * DMODEL * 2);
    float* x2   = (float*)alloc((size_t)NROWS * DMODEL * 4);
    float* yf   = (float*)alloc((size_t)NROWS * DMODEL * 4);
    u16*   yb   = (u16*)  alloc((size_t)NROWS * DMODEL * 2);
    u16*   hb   = (u16*)  alloc((size_t)NROWS * DFF * 2);
    u16*   wqkv = (u16*)  alloc((size_t)768 * 256 * 2);
    u16*   wob  = (u16*)  alloc((size_t)256 * 256 * 2);
    u16*   w1b  = (u16*)  alloc((size_t)1024 * 256 * 2);
    u16*   w2b  = (u16*)  alloc((size_t)256 * 1024 * 2);
    float* bq   = (float*)alloc(768 * 4);

    convert_weights<<<3072, 256, 0, stream>>>(ipw, outw, w1, w2, ipb, wqkv, wob, w1b, w2b, bq);
    ln_kernel<<<2048, 256, 0, stream>>>(src, g1, be1, xf, xb);
    gemm_bt<0><<<dim3(128, 12), 256, 0, stream>>>(xb, wqkv, bq, nullptr, nullptr, qkv, NROWS, 768, 256);
    reshape_qkv<<<3072, 256, 0, stream>>>(qkv, Qb, Kb, Vt);
    attn_kernel<<<dim3(16, 64), 256, 0, stream>>>(Qb, Kb, Vt, bias, ctx);
    gemm_bt<1><<<dim3(128, 4), 256, 0, stream>>>(ctx, wob, outb, xf, x2, nullptr, NROWS, 256, 256);
    ln_kernel<<<2048, 256, 0, stream>>>(x2, g2, be2, yf, yb);
    gemm_bt<2><<<dim3(128, 16), 256, 0, stream>>>(yb, w1b, b1, nullptr, nullptr, hb, NROWS, 1024, 256);
    gemm_bt<3><<<dim3(128, 4), 256, 0, stream>>>(hb, w2b, b2, yf, (float*)d_out, nullptr, NROWS, 256, 1024);
}